// Round 10
// baseline (188.820 us; speedup 1.0000x reference)
//
#include <hip/hip_runtime.h>
#include <hip/hip_bf16.h>

typedef __hip_bfloat16 bh;
typedef __attribute__((ext_vector_type(8))) __bf16 bf16x8;
typedef __attribute__((ext_vector_type(4))) float f32x4;
typedef __attribute__((ext_vector_type(4))) int i32x4;
typedef __attribute__((ext_vector_type(4))) short s16x4;

#define NB 2
#define NL 4096
#define NC 512
#define NH 8
#define NDH 64
#define NM (NB * NL)          // 8192
#define LOG2E 1.4426950408889634f
#define KVBLK 8192            // elems per (bh,kt): 8KB K frags + 8KB V frags

static __device__ __forceinline__ f32x4 mfma_bf16(bf16x8 a, bf16x8 b, f32x4 c) {
    return __builtin_amdgcn_mfma_f32_16x16x32_bf16(a, b, c, 0, 0, 0);
}
static __device__ __forceinline__ f32x4 mfma16(s16x4 a, s16x4 b, f32x4 c) {
    return __builtin_amdgcn_mfma_f32_16x16x16bf16_1k(a, b, c, 0, 0, 0);
}

static __device__ __forceinline__ void st_bf4(bh* dst, float a, float b, float c, float d) {
    bh tmp[4] = {__float2bfloat16(a), __float2bfloat16(b),
                 __float2bfloat16(c), __float2bfloat16(d)};
    *(s16x4*)dst = *(const s16x4*)tmp;
}
static __device__ __forceinline__ s16x4 pk_bf4(float a, float b, float c, float d) {
    bh tmp[4] = {__float2bfloat16(a), __float2bfloat16(b),
                 __float2bfloat16(c), __float2bfloat16(d)};
    return *(const s16x4*)tmp;
}

static __device__ __forceinline__ void gload16(const bh* g, bh* l) {
    __builtin_amdgcn_global_load_lds(
        (const __attribute__((address_space(1))) void*)g,
        (__attribute__((address_space(3))) void*)l,
        16, 0, 0);
}

// ---------------------------------------------------------------------------
// Kernel 0: combined prep (unchanged).
// ---------------------------------------------------------------------------
__global__ __launch_bounds__(256, 2)
void prep(const float* __restrict__ x,
          const float* __restrict__ Wq, const float* __restrict__ Wk,
          const float* __restrict__ Wv, const float* __restrict__ Wo,
          bh* __restrict__ xf, bh* __restrict__ Wf)
{
    const int t = threadIdx.x;
    const int wave = t >> 6, lane = t & 63;
    const int quad = lane >> 4, c16 = lane & 15;

    if (blockIdx.z < 8) {
        __shared__ __align__(16) bh T[64][72];
        const int m64 = blockIdx.x, k64 = blockIdx.z;
        #pragma unroll
        for (int rep = 0; rep < 4; rep++) {
            int li = t + rep * 256;
            int r = li >> 4, c4 = (li & 15) * 4;
            float4 f = *(const float4*)&x[(size_t)(m64 * 64 + r) * 512 + k64 * 64 + c4];
            st_bf4(&T[r][c4], f.x, f.y, f.z, f.w);
        }
        __syncthreads();
        #pragma unroll
        for (int kcl = 0; kcl < 2; kcl++) {
            i32x4 v = *(const i32x4*)&T[wave * 16 + c16][kcl * 32 + quad * 8];
            size_t addr = ((size_t)(m64 * 4 + wave) * 16 + (k64 * 2 + kcl)) * 512 + lane * 8;
            *(i32x4*)&xf[addr] = v;
        }
    } else {
        if (blockIdx.x >= 64) return;
        int task = blockIdx.x * 4 + wave;
        int z = task >> 6, nt = (task >> 3) & 7, k0i = task & 7;
        const float* W = (z == 0) ? Wq : (z == 1) ? Wk : (z == 2) ? Wv : Wo;
        bh* dst = Wf + (((size_t)z * 8 + nt) * 8 + k0i) * 4096;
        #pragma unroll
        for (int kc = 0; kc < 2; kc++)
            #pragma unroll
            for (int fn = 0; fn < 4; fn++) {
                bh tmp[8];
                #pragma unroll
                for (int j = 0; j < 8; j++)
                    tmp[j] = __float2bfloat16(
                        W[(size_t)(k0i * 64 + kc * 32 + quad * 8 + j) * 512
                          + nt * 64 + fn * 16 + c16]);
                *(i32x4*)&dst[(kc * 4 + fn) * 512 + lane * 8] = *(const i32x4*)tmp;
            }
    }
}

// ---------------------------------------------------------------------------
// Kernel 1: fused QKV projection, v5: 64-row m-tiles, grid 1024 = 4 blocks/CU
// (16 waves/CU). X staging is WAVE-PRIVATE (wave stages only its own m16
// frags, double-buffered); W single-buffered (L2-hot). LDS exactly 40 KB.
// ---------------------------------------------------------------------------
__global__ __launch_bounds__(256, 4)
void qkv_gemm(const bh* __restrict__ xf, const bh* __restrict__ Wf,
              bh* __restrict__ Qb, bh* __restrict__ KVf)
{
    __shared__ __align__(16) bh Xl[2][4096];   // [buf][wave*1024 + kcl*512 + lane*8]
    __shared__ __align__(16) bh Wl[3 * 4096];  // 24 KB, single-buffered

    const int t = threadIdx.x;
    const int wave = t >> 6, lane = t & 63;
    const int quad = lane >> 4, c16 = lane & 15;
    const int m0 = blockIdx.x * 64;
    const int nt = blockIdx.y;
    const int m16 = (m0 >> 4) + wave;          // this wave's global m16 index

    f32x4 acc[3][4];
    for (int z = 0; z < 3; z++)
        for (int b = 0; b < 4; b++)
            for (int u = 0; u < 4; u++) acc[z][b][u] = 0.0f;

    auto stageX = [&](int k0i, int buf) {
        #pragma unroll
        for (int kcl = 0; kcl < 2; kcl++) {
            const bh* src = xf + ((size_t)m16 * 16 + k0i * 2 + kcl) * 512 + lane * 8;
            gload16(src, &Xl[buf][wave * 1024 + kcl * 512 + lane * 8]);
        }
    };
    auto stageW = [&](int k0i) {
        #pragma unroll
        for (int z = 0; z < 3; z++) {
            const bh* wz = Wf + (((size_t)z * 8 + nt) * 8 + k0i) * 4096;
            #pragma unroll
            for (int r = 0; r < 2; r++) {
                int off = (wave * 2 + r) * 512 + lane * 8;
                gload16(wz + off, &Wl[z * 4096 + off]);
            }
        }
    };

    stageX(0, 0);
    stageW(0);
    for (int k0i = 0; k0i < 8; k0i++) {
        const int buf = k0i & 1;
        __syncthreads();                       // staging for k0i landed everywhere
        if (k0i < 7) stageX(k0i + 1, buf ^ 1); // wave-private prefetch
        #pragma unroll
        for (int kc = 0; kc < 2; kc++) {
            bf16x8 af = *(const bf16x8*)&Xl[buf][wave * 1024 + kc * 512 + lane * 8];
            #pragma unroll
            for (int z = 0; z < 3; z++)
                #pragma unroll
                for (int fn = 0; fn < 4; fn++) {
                    bf16x8 bf = *(const bf16x8*)&Wl[z * 4096 + (kc * 4 + fn) * 512 + lane * 8];
                    acc[z][fn] = mfma_bf16(af, bf, acc[z][fn]);
                }
        }
        __syncthreads();                       // all waves done reading Wl
        if (k0i < 7) stageW(k0i + 1);          // safe to overwrite now
    }

    const int h = nt;
    const int b = m0 >> 12;
    const int l0 = m0 & 4095;
    const int bh_i = b * NH + h;
    const int kt0 = l0 >> 6;                   // the single kt this block covers

    // ---- Phase Q: LDS transpose (rows 64 x 68), coalesced copy-out.
    {
        bh* Tq = &Wl[0];                       // 8704 B, W dead now
        #pragma unroll
        for (int i = 0; i < 4; i++) {
            int ll = wave * 16 + quad * 4 + i;
            #pragma unroll
            for (int fn = 0; fn < 4; fn++)
                Tq[ll * 68 + fn * 16 + c16] =
                    __float2bfloat16(acc[0][fn][i] * 0.125f);
        }
        __syncthreads();
        int l = t >> 2, qtr = t & 3;           // 64 rows x 4 chunks of 16 elems
        bh* dst = Qb + ((size_t)bh_i * NL + l0 + l) * NDH + qtr * 16;
        const bh* src = &Tq[l * 68 + qtr * 16];
        *(i32x4*)(dst + 0) = *(const i32x4*)(src + 0);
        *(i32x4*)(dst + 8) = *(const i32x4*)(src + 8);
        __syncthreads();
    }

    // ---- Phase K: LDS scatter into KVf frag image (xLOG2E), coalesced copy-out.
    {
        bh* Tk = &Wl[0];                       // 8 KB frag image for one kt
        #pragma unroll
        for (int i = 0; i < 4; i++) {
            int ll = wave * 16 + quad * 4 + i;
            int fk = wave, c16t = ll & 15;     // fk == wave for 64-row tile
            #pragma unroll
            for (int fn = 0; fn < 4; fn++) {
                int d = fn * 16 + c16;
                int kc = d >> 5, qt = (d >> 3) & 3, j = d & 7;
                Tk[(fk * 2 + kc) * 512 + (qt * 16 + c16t) * 8 + j] =
                    __float2bfloat16(acc[1][fn][i] * LOG2E);
            }
        }
        __syncthreads();
        bh* dst = KVf + (size_t)(bh_i * 64 + kt0) * KVBLK + t * 16;
        *(i32x4*)(dst + 0) = *(const i32x4*)&Tk[t * 16 + 0];
        *(i32x4*)(dst + 8) = *(const i32x4*)&Tk[t * 16 + 8];
    }

    // ---- V: direct frag stores; wave w == fk. b64, lane-contiguous.
    #pragma unroll
    for (int fn = 0; fn < 4; fn++) {
        size_t addr = (size_t)(bh_i * 64 + kt0) * KVBLK + 4096
                    + (size_t)(fn * 4 + wave) * 256 + (quad * 16 + c16) * 4;
        st_bf4(&KVf[addr], acc[2][fn][0], acc[2][fn][1],
                           acc[2][fn][2], acc[2][fn][3]);
    }
}

// ---------------------------------------------------------------------------
// Kernel 2: flash attention — IDENTICAL to R9 (isolating the GEMM experiment).
// ---------------------------------------------------------------------------
__global__ __launch_bounds__(512, 4)
void flash_attn(const bh* __restrict__ Qb, const bh* __restrict__ KVf,
                bh* __restrict__ attb)
{
    __shared__ __align__(16) bh SF[2][2][KVBLK];   // [group][buf], 64 KB

    const int t = threadIdx.x;
    const int wave = t >> 6, lane = t & 63;
    const int group = wave >> 2, w4 = wave & 3;
    const int quad = lane >> 4, c16 = lane & 15;
    const int bh_idx = blockIdx.y;
    const int q0 = blockIdx.x * 128;

    const bh* Qp  = Qb + (size_t)bh_idx * NL * NDH;
    const bh* KVp = KVf + (size_t)bh_idx * 64 * KVBLK;

    bf16x8 qf[2][2];
    #pragma unroll
    for (int fq = 0; fq < 2; fq++)
        #pragma unroll
        for (int kc = 0; kc < 2; kc++)
            qf[fq][kc] = *(const bf16x8*)
                &Qp[(size_t)(q0 + w4 * 32 + fq * 16 + c16) * NDH + kc * 32 + quad * 8];

    f32x4 ot[4][2];
    float lsum[2] = {0.0f, 0.0f};
    for (int a = 0; a < 4; a++)
        for (int fq = 0; fq < 2; fq++)
            for (int u = 0; u < 4; u++) ot[a][fq][u] = 0.0f;
    const f32x4 z4 = {0.0f, 0.0f, 0.0f, 0.0f};

    auto stage = [&](int i, int buf) {
        int kt = 2 * i + group;
        #pragma unroll
        for (int r = 0; r < 4; r++) {
            int off = (w4 * 4 + r) * 512 + lane * 8;
            gload16(KVp + (size_t)kt * KVBLK + off, &SF[group][buf][off]);
        }
    };

    stage(0, 0);
    for (int i = 0; i < 32; i++) {
        const int buf = i & 1;
        __syncthreads();
        if (i < 31) stage(i + 1, buf ^ 1);
        const bh* sf = &SF[group][buf][0];

        f32x4 s[4][2];
        #pragma unroll
        for (int fk = 0; fk < 4; fk++) {
            bf16x8 kf0 = *(const bf16x8*)&sf[(fk * 2 + 0) * 512 + lane * 8];
            s[fk][0] = mfma_bf16(kf0, qf[0][0], z4);
            s[fk][1] = mfma_bf16(kf0, qf[1][0], z4);
        }
        #pragma unroll
        for (int fk = 0; fk < 4; fk++) {
            bf16x8 kf1 = *(const bf16x8*)&sf[(fk * 2 + 1) * 512 + lane * 8];
            s[fk][0] = mfma_bf16(kf1, qf[0][1], s[fk][0]);
            s[fk][1] = mfma_bf16(kf1, qf[1][1], s[fk][1]);
        }

        s16x4 vt[4][4];
        #pragma unroll
        for (int fn = 0; fn < 4; fn++)
            #pragma unroll
            for (int fk = 0; fk < 4; fk++)
                vt[fn][fk] = *(const s16x4*)&sf[4096 + (fn * 4 + fk) * 256 + lane * 4];

        s16x4 pf[4][2];
        float rs0 = 0.0f, rs1 = 0.0f;
        #pragma unroll
        for (int fk = 0; fk < 4; fk++) {
            float a0 = __builtin_amdgcn_exp2f(s[fk][0][0]);
            float a1 = __builtin_amdgcn_exp2f(s[fk][0][1]);
            float a2 = __builtin_amdgcn_exp2f(s[fk][0][2]);
            float a3 = __builtin_amdgcn_exp2f(s[fk][0][3]);
            rs0 += (a0 + a1) + (a2 + a3);
            pf[fk][0] = pk_bf4(a0, a1, a2, a3);
            float b0 = __builtin_amdgcn_exp2f(s[fk][1][0]);
            float b1 = __builtin_amdgcn_exp2f(s[fk][1][1]);
            float b2 = __builtin_amdgcn_exp2f(s[fk][1][2]);
            float b3 = __builtin_amdgcn_exp2f(s[fk][1][3]);
            rs1 += (b0 + b1) + (b2 + b3);
            pf[fk][1] = pk_bf4(b0, b1, b2, b3);
        }
        lsum[0] += rs0;
        lsum[1] += rs1;

        #pragma unroll
        for (int fk = 0; fk < 4; fk++)
            #pragma unroll
            for (int fn = 0; fn < 4; fn++) {
                ot[fn][0] = mfma16(vt[fn][fk], pf[fk][0], ot[fn][0]);
                ot[fn][1] = mfma16(vt[fn][fk], pf[fk][1], ot[fn][1]);
            }
    }

    #pragma unroll
    for (int fq = 0; fq < 2; fq++) {
        lsum[fq] += __shfl_xor(lsum[fq], 16);
        lsum[fq] += __shfl_xor(lsum[fq], 32);
    }

    float* Ocmb = (float*)&SF[0][0][0];
    float* Lcmb = Ocmb + 128 * 64;
    __syncthreads();
    if (group == 1) {
        #pragma unroll
        for (int fq = 0; fq < 2; fq++) {
            int q = w4 * 32 + fq * 16 + c16;
            #pragma unroll
            for (int fn = 0; fn < 4; fn++)
                *(f32x4*)&Ocmb[q * 64 + fn * 16 + quad * 4] = ot[fn][fq];
            if (quad == 0) Lcmb[q] = lsum[fq];
        }
    }
    __syncthreads();
    if (group == 0) {
        const int b = bh_idx >> 3, h = bh_idx & 7;
        const int mbase16 = (b * NL + q0) >> 4;
        #pragma unroll
        for (int fq = 0; fq < 2; fq++) {
            int q = w4 * 32 + fq * 16 + c16;
            float inv = 1.0f / (lsum[fq] + Lcmb[q]);
            int m16 = mbase16 + w4 * 2 + fq;
            #pragma unroll
            for (int fn = 0; fn < 4; fn++) {
                f32x4 o2 = *(const f32x4*)&Ocmb[q * 64 + fn * 16 + quad * 4];
                size_t addr = ((size_t)m16 * 16 + h * 2 + (fn >> 1)) * 512
                            + (size_t)(((fn & 1) * 2 + (quad >> 1)) * 16 + c16) * 8
                            + (quad & 1) * 4;
                st_bf4(&attb[addr],
                       (ot[fn][fq][0] + o2[0]) * inv, (ot[fn][fq][1] + o2[1]) * inv,
                       (ot[fn][fq][2] + o2[2]) * inv, (ot[fn][fq][3] + o2[3]) * inv);
            }
        }
    }
}

// ---------------------------------------------------------------------------
// Kernel 3: out = att(A-frag) @ Wo + bo -> fp32.  v2: 64-row tiles,
// grid 1024 = 4 blocks/CU, wave-private X dbuf, W single-buffered. 24 KB LDS.
// ---------------------------------------------------------------------------
__global__ __launch_bounds__(256, 4)
void out_gemm(const bh* __restrict__ Af, const bh* __restrict__ Wf,
              const float* __restrict__ bo, float* __restrict__ out)
{
    __shared__ __align__(16) bh Xl[2][4096];
    __shared__ __align__(16) bh Wl[4096];

    const int t = threadIdx.x;
    const int wave = t >> 6, lane = t & 63;
    const int quad = lane >> 4, c16 = lane & 15;
    const int m0 = blockIdx.x * 64;
    const int nt = blockIdx.y;
    const int n0 = nt * 64;
    const int m16 = (m0 >> 4) + wave;

    f32x4 acc[4];
    for (int b = 0; b < 4; b++)
        for (int u = 0; u < 4; u++) acc[b][u] = 0.0f;

    auto stageX = [&](int k0i, int buf) {
        #pragma unroll
        for (int kcl = 0; kcl < 2; kcl++) {
            const bh* src = Af + ((size_t)m16 * 16 + k0i * 2 + kcl) * 512 + lane * 8;
            gload16(src, &Xl[buf][wave * 1024 + kcl * 512 + lane * 8]);
        }
    };
    auto stageW = [&](int k0i) {
        const bh* wz = Wf + (((size_t)3 * 8 + nt) * 8 + k0i) * 4096;
        #pragma unroll
        for (int r = 0; r < 2; r++) {
            int off = (wave * 2 + r) * 512 + lane * 8;
            gload16(wz + off, &Wl[off]);
        }
    };

    stageX(0, 0);
    stageW(0);
    for (int k0i = 0; k0i < 8; k0i++) {
        const int buf = k0i & 1;
        __syncthreads();
        if (k0i < 7) stageX(k0i + 1, buf ^ 1);
        #pragma unroll
        for (int kc = 0; kc < 2; kc++) {
            bf16x8 af = *(const bf16x8*)&Xl[buf][wave * 1024 + kc * 512 + lane * 8];
            #pragma unroll
            for (int fn = 0; fn < 4; fn++) {
                bf16x8 bf = *(const bf16x8*)&Wl[(kc * 4 + fn) * 512 + lane * 8];
                acc[fn] = mfma_bf16(af, bf, acc[fn]);
            }
        }
        __syncthreads();
        if (k0i < 7) stageW(k0i + 1);
    }

    #pragma unroll
    for (int i = 0; i < 4; i++) {
        int mr = m0 + wave * 16 + quad * 4 + i;
        #pragma unroll
        for (int fn = 0; fn < 4; fn++) {
            int cn = n0 + fn * 16 + c16;
            out[(size_t)mr * 512 + cn] = acc[fn][i] + bo[cn];
        }
    }
}

// ---------------------------------------------------------------------------
extern "C" void kernel_launch(void* const* d_in, const int* in_sizes, int n_in,
                              void* d_out, int out_size, void* d_ws, size_t ws_size,
                              hipStream_t stream)
{
    const float* x  = (const float*)d_in[0];
    const float* Wq = (const float*)d_in[1];
    const float* Wk = (const float*)d_in[2];
    const float* Wv = (const float*)d_in[3];
    const float* Wo = (const float*)d_in[4];
    const float* bo = (const float*)d_in[5];
    float* out = (float*)d_out;

    const size_t mat = (size_t)NM * NC;       // 4 Mi elems (8 MB bf16)
    bh* Qb   = (bh*)d_ws;                     //  8 MB
    bh* KVf  = Qb + mat;                      // 16 MB
    bh* attb = KVf + 2 * mat;                 //  8 MB (A-frag layout)
    bh* Wf   = attb + mat;                    //  2 MB
    bh* xf   = Wf + 4 * 8 * 8 * 4096;         //  8 MB

    prep      <<<dim3(128, 1, 9),         256, 0, stream>>>(x, Wq, Wk, Wv, Wo, xf, Wf);
    qkv_gemm  <<<dim3(NM / 64, NC / 64),  256, 0, stream>>>(xf, Wf, Qb, KVf);
    flash_attn<<<dim3(NL / 128, NB * NH), 512, 0, stream>>>(Qb, KVf, attb);
    out_gemm  <<<dim3(NM / 64, NC / 64),  256, 0, stream>>>(attb, Wf, bo, out);
}